// Round 5
// baseline (274.624 us; speedup 1.0000x reference)
//
#include <hip/hip_runtime.h>
#include <math.h>

#define HQ   12
#define DH   64
#define NSEQ 1024
#define BB   4
#define DIMM 768
#define RR   8
#define BHD  (BB*HQ)      // 48
#define MROWS (BB*NSEQ)   // 4096
#define OUT_ELEMS (BB*NSEQ*DIMM)  // 3145728

typedef short bf16x8 __attribute__((ext_vector_type(8)));
typedef float f32x4  __attribute__((ext_vector_type(4)));

__device__ __forceinline__ unsigned short f2bf(float f) {
    union { float f; unsigned u; } x; x.f = f;
    return (unsigned short)((x.u + 0x7fffu + ((x.u >> 16) & 1u)) >> 16);
}
__device__ __forceinline__ float bf2f(unsigned short b) {
    union { unsigned u; float f; } x; x.u = ((unsigned)b) << 16;
    return x.f;
}

#define AS_GLOBAL(p) ((const __attribute__((address_space(1))) void*)(p))
#define AS_LDS(p)    ((__attribute__((address_space(3))) void*)(p))

// ---------------------------------------------------------------------------
// fp32 -> bf16 conversion: x (seg 0), wq/wk/wv -> fused wf (segs 1-3), wo (4)
// ---------------------------------------------------------------------------
__global__ __launch_bounds__(256)
void convert_kernel(const float* __restrict__ x,  const float* __restrict__ wq,
                    const float* __restrict__ wk, const float* __restrict__ wv,
                    const float* __restrict__ wo, unsigned short* __restrict__ xb,
                    unsigned short* __restrict__ wf, unsigned short* __restrict__ wob)
{
    const int seg = blockIdx.y;
    const float* src; unsigned short* dst; int n4;
    if      (seg == 0) { src = x;  dst = xb;            n4 = 786432; }
    else if (seg == 1) { src = wq; dst = wf;            n4 = 147456; }
    else if (seg == 2) { src = wk; dst = wf + 589824;   n4 = 147456; }
    else if (seg == 3) { src = wv; dst = wf + 1179648;  n4 = 147456; }
    else               { src = wo; dst = wob;           n4 = 147456; }
    for (int i = blockIdx.x*256 + threadIdx.x; i < n4; i += gridDim.x*256) {
        float4 v = ((const float4*)src)[i];
        unsigned lo = (unsigned)f2bf(v.x) | ((unsigned)f2bf(v.y) << 16);
        unsigned hi = (unsigned)f2bf(v.z) | ((unsigned)f2bf(v.w) << 16);
        ((uint2*)dst)[i] = make_uint2(lo, hi);
    }
}

// ---------------------------------------------------------------------------
// MFMA GEMM, m97 structure: 128x128 tile, BK=32, 4 waves x (4x4 16x16x32).
// MODE 0 (QKV fused, grid 18x32):
//   bx<6: Q -> qb fp32 (b,h,n,d); 6<=bx<12: K -> kb fp32 (b,h,n,d)
//   bx>=12: V with A/B swapped (acc = C^T) -> vt bf16 (bh,d,n)
// MODE 1 (O-proj, grid 6x32): A = attn bf16 [4096][768], out fp32 + bias
// ---------------------------------------------------------------------------
template<int MODE>
__global__ __launch_bounds__(256)
void mfma_gemm(const unsigned short* __restrict__ X,
               const unsigned short* __restrict__ Wf,
               const float* __restrict__ bias,
               float* __restrict__ qb, float* __restrict__ kb,
               unsigned short* __restrict__ vt, float* __restrict__ outp)
{
    __shared__ unsigned short As[128*32];   // 8 KB, unpadded (global_load_lds)
    __shared__ unsigned short Bs[128*32];
    const int tid  = threadIdx.x;
    const int lane = tid & 63;
    const int qr   = lane & 15, quad = lane >> 4;
    const int wid  = tid >> 6;
    const int w_m  = wid >> 1, w_n = wid & 1;
    const int bx = blockIdx.x, by = blockIdx.y;

    const bool vmode = (MODE == 0) && (bx >= 12);
    const unsigned short* Abase = vmode ? (Wf + bx*128*768) : (X + by*128*768);
    const unsigned short* Bbase = vmode ? (X + by*128*768) : (Wf + bx*128*768);

    const int row0 = tid >> 2;          // 0..63
    const int segk = (tid & 3) * 8;     // k offset 0/8/16/24

    f32x4 acc[4][4] = {};

    for (int kt = 0; kt < 768; kt += 32) {
        __syncthreads();   // previous tile fully consumed
        const unsigned short* ga = Abase + row0*768 + kt + segk;
        const unsigned short* gb = Bbase + row0*768 + kt + segk;
        __builtin_amdgcn_global_load_lds(AS_GLOBAL(ga),          AS_LDS(&As[tid*8]),        16, 0, 0);
        __builtin_amdgcn_global_load_lds(AS_GLOBAL(ga + 64*768), AS_LDS(&As[2048 + tid*8]), 16, 0, 0);
        __builtin_amdgcn_global_load_lds(AS_GLOBAL(gb),          AS_LDS(&Bs[tid*8]),        16, 0, 0);
        __builtin_amdgcn_global_load_lds(AS_GLOBAL(gb + 64*768), AS_LDS(&Bs[2048 + tid*8]), 16, 0, 0);
        __syncthreads();   // implicit vmcnt(0) drain

        bf16x8 a[4], b[4];
        #pragma unroll
        for (int mi = 0; mi < 4; ++mi)
            a[mi] = *(const bf16x8*)&As[(w_m*64 + mi*16 + qr)*32 + quad*8];
        #pragma unroll
        for (int ni = 0; ni < 4; ++ni)
            b[ni] = *(const bf16x8*)&Bs[(w_n*64 + ni*16 + qr)*32 + quad*8];
        #pragma unroll
        for (int mi = 0; mi < 4; ++mi)
            #pragma unroll
            for (int ni = 0; ni < 4; ++ni)
                acc[mi][ni] = __builtin_amdgcn_mfma_f32_16x16x32_bf16(a[mi], b[ni], acc[mi][ni], 0, 0, 0);
    }

    if (MODE == 1) {
        #pragma unroll
        for (int ni = 0; ni < 4; ++ni) {
            const int i = bx*128 + w_n*64 + ni*16 + qr;
            const float bs = bias[i];
            #pragma unroll
            for (int mi = 0; mi < 4; ++mi) {
                const int m0 = by*128 + w_m*64 + mi*16 + quad*4;
                #pragma unroll
                for (int r = 0; r < 4; ++r)
                    outp[(m0 + r)*768 + i] = acc[mi][ni][r] + bs;
            }
        }
    } else if (!vmode) {
        float* dst; int chb;
        if (bx < 6) { dst = qb; chb = bx*128; } else { dst = kb; chb = bx*128 - 768; }
        #pragma unroll
        for (int ni = 0; ni < 4; ++ni) {
            const int i = chb + w_n*64 + ni*16 + qr;
            const int h = i >> 6, d = i & 63;
            #pragma unroll
            for (int mi = 0; mi < 4; ++mi) {
                const int m0 = by*128 + w_m*64 + mi*16 + quad*4;
                #pragma unroll
                for (int r = 0; r < 4; ++r) {
                    const int m = m0 + r;
                    const int b = m >> 10, n = m & 1023;
                    dst[((((b*HQ + h) << 10) + n) << 6) + d] = acc[mi][ni][r];
                }
            }
        }
    } else {
        const int chb = bx*128 - 1536;
        #pragma unroll
        for (int mi = 0; mi < 4; ++mi) {
            #pragma unroll
            for (int r = 0; r < 4; ++r) {
                const int i = chb + w_m*64 + mi*16 + quad*4 + r;   // V channel
                const int h = i >> 6, d = i & 63;
                #pragma unroll
                for (int ni = 0; ni < 4; ++ni) {
                    const int mcol = by*128 + w_n*64 + ni*16 + qr; // seq index
                    const int b = mcol >> 10, n = mcol & 1023;
                    vt[((((b*HQ + h) << 6) + d) << 10) + n] = f2bf(acc[mi][ni][r]);
                }
            }
        }
    }
}

// ---------------------------------------------------------------------------
// SPD projection (q and k fused via blockIdx.y).
// Emits bf16 log-vectors + fp32 norms computed on the ROUNDED values so that
// d2 = nq + nk - 2*dot_bf16 stays consistent (>= ~0).
// ---------------------------------------------------------------------------
__global__ __launch_bounds__(256)
void spd_kernel(const float* __restrict__ qb, const float* __restrict__ kb,
                const float* __restrict__ sqw, const float* __restrict__ sqb,
                const float* __restrict__ skw, const float* __restrict__ skb,
                unsigned short* __restrict__ lqo, unsigned short* __restrict__ lko,
                float* __restrict__ nqo, float* __restrict__ nko)
{
    const int which = blockIdx.y;
    const float* src = which ? kb  : qb;
    const float* wp0 = which ? skw : sqw;
    const float* bp  = which ? skb : sqb;
    unsigned short* lo = which ? lko : lqo;
    float* no = which ? nko : nqo;

    const int tid = threadIdx.x;
    const int r = tid & 7;
    const int row = blockIdx.x * 32 + (tid >> 3);
    const float* qp = src + row*64;
    const float* wp = wp0 + r*64;
    float acc = bp[r];
    #pragma unroll
    for (int d = 0; d < 64; ++d) acc += qp[d] * wp[d];
    float sp = (acc > 0.f) ? (acc + log1pf(__expf(-acc))) : log1pf(__expf(acc));
    float l = __logf(sp + 1e-6f + 1e-8f);
    const unsigned short lb = f2bf(l);
    lo[row*8 + r] = lb;
    const float lr = bf2f(lb);
    float s = lr * lr;
    s += __shfl_xor(s, 1);
    s += __shfl_xor(s, 2);
    s += __shfl_xor(s, 4);
    if (r == 0) no[row] = s;
}

// ---------------------------------------------------------------------------
// Attention v4: split-K flash-decode. Grid (16, 48, 4): z = key partition
// (256 keys = 4 chunks of 64). Block = 64 queries of one bh, 4 waves.
// Emits UNNORMALIZED partial O (bf16) + partial wsum (fp32); attn_reduce
// combines. 3072 blocks -> 12 blocks/CU -> occupancy-capped ~32 waves/CU,
// hiding the per-chunk lk->S-MFMA->trans->LDS->vt->PV-MFMA latency chain.
// ---------------------------------------------------------------------------
__global__ __launch_bounds__(256)
void attn_kernel(const unsigned short* __restrict__ lq,
                 const unsigned short* __restrict__ lk,
                 const float* __restrict__ nq, const float* __restrict__ nk,
                 const unsigned short* __restrict__ vt,
                 unsigned short* __restrict__ po, float* __restrict__ pw)
{
    __shared__ unsigned short w_s[64*72];   // 9 KB, stride 72 (9 granules)

    const int tid  = threadIdx.x;
    const int lane = tid & 63;
    const int wid  = tid >> 6;
    const int qr   = lane & 15;
    const int quad = lane >> 4;
    const int bh   = blockIdx.y;
    const int p    = blockIdx.z;
    const int c0   = p << 8;
    const int q0   = blockIdx.x*64 + wid*16;
    const int qrow = (bh << 10) + q0 + qr;

    bf16x8 bq = {};
    if (quad == 0) bq = *(const bf16x8*)(lq + qrow*8);
    const float nqv = nq[qrow];

    f32x4 acc[4] = {};
    float wsum_acc = 0.f;

    const unsigned short* vtg = vt + (bh << 16);   // bh*64*1024
    const unsigned short* lkg = lk + (bh << 13);   // bh*1024*8
    const float*          nkg = nk + (bh << 10);

    for (int c = c0; c < c0 + 256; c += 64) {
        float wsum_c = 0.f;
        unsigned wpk[4][2];
        #pragma unroll
        for (int kb = 0; kb < 4; ++kb) {
            bf16x8 ak = {};
            if (quad == 0) ak = *(const bf16x8*)(lkg + (c + kb*16 + qr)*8);
            f32x4 s = {};
            s = __builtin_amdgcn_mfma_f32_16x16x32_bf16(ak, bq, s, 0, 0, 0);
            const float4 nk4 = *(const float4*)(nkg + c + kb*16 + quad*4);
            const float nkv[4] = {nk4.x, nk4.y, nk4.z, nk4.w};
            float w[4];
            #pragma unroll
            for (int r = 0; r < 4; ++r) {
                const float d2 = nqv + nkv[r] - 2.f*s[r];
                const float dist = sqrtf(fmaxf(d2, 1e-12f));
                w[r] = __expf(-0.125f * dist);
                wsum_c += w[r];
            }
            wpk[kb][0] = (unsigned)f2bf(w[0]) | ((unsigned)f2bf(w[1]) << 16);
            wpk[kb][1] = (unsigned)f2bf(w[2]) | ((unsigned)f2bf(w[3]) << 16);
        }
        #pragma unroll
        for (int kb = 0; kb < 4; ++kb)
            *(uint2*)&w_s[(wid*16 + qr)*72 + kb*16 + quad*4] =
                make_uint2(wpk[kb][0], wpk[kb][1]);
        wsum_c += __shfl_xor(wsum_c, 16);
        wsum_c += __shfl_xor(wsum_c, 32);
        wsum_acc += wsum_c;

        #pragma unroll
        for (int s2 = 0; s2 < 2; ++s2) {
            const bf16x8 af = *(const bf16x8*)&w_s[(wid*16 + qr)*72 + s2*32 + quad*8];
            #pragma unroll
            for (int jb = 0; jb < 4; ++jb) {
                const bf16x8 bv = *(const bf16x8*)(vtg + ((jb*16 + qr) << 10) + c + s2*32 + quad*8);
                acc[jb] = __builtin_amdgcn_mfma_f32_16x16x32_bf16(af, bv, acc[jb], 0, 0, 0);
            }
        }
    }

    // epilogue: unnormalized partials. po[p][bh][q][d] bf16, pw[p][bh][q] fp32
    unsigned short* pob = po + ((p*BHD + bh) << 16);
    #pragma unroll
    for (int jb = 0; jb < 4; ++jb) {
        #pragma unroll
        for (int r = 0; r < 4; ++r) {
            const int q = quad*4 + r;
            const int d = jb*16 + qr;
            pob[((q0 + q) << 6) + d] = f2bf(acc[jb][r]);
        }
    }
    if (quad == 0)
        pw[((p*BHD + bh) << 10) + q0 + qr] = wsum_acc;
}

// ---------------------------------------------------------------------------
// Combine split-K partials: out = (sum_p po) / (sum_p pw), bf16 [n][h*64+d]
// ---------------------------------------------------------------------------
__global__ __launch_bounds__(256)
void attn_reduce(const unsigned short* __restrict__ po,
                 const float* __restrict__ pw, unsigned short* __restrict__ out)
{
    const int flat = blockIdx.x*256 + threadIdx.x;   // < 3145728
    const int bh = flat >> 16;
    const int q  = (flat >> 6) & 1023;
    const int d  = flat & 63;
    float s = 0.f, wsum = 0.f;
    #pragma unroll
    for (int p = 0; p < 4; ++p) {
        s    += bf2f(po[p*3145728 + flat]);
        wsum += pw[((p*BHD + bh) << 10) + q];
    }
    const int bb = bh / HQ, hh = bh - bb*HQ;
    out[((bb << 10) + q)*768 + hh*64 + d] = f2bf(s / wsum);
}

// ---------------------------------------------------------------------------
// KL reduction (unchanged)
// ---------------------------------------------------------------------------
__global__ __launch_bounds__(256)
void kl_partial_kernel(const float* __restrict__ mu0, const float* __restrict__ ls0,
                       const float* __restrict__ mu1, const float* __restrict__ ls1,
                       const float* __restrict__ mu2, const float* __restrict__ ls2,
                       const float* __restrict__ mu3, const float* __restrict__ ls3,
                       double* __restrict__ partials)
{
    const int tid = threadIdx.x;
    double acc = 0.0;
    for (int idx = blockIdx.x*256 + tid; idx < 589824; idx += 256*256) {
        float m, l;
        m = mu0[idx]; l = ls0[idx]; acc += (double)(expf(2.f*l) + m*m - 1.f - 2.f*l);
        m = mu1[idx]; l = ls1[idx]; acc += (double)(expf(2.f*l) + m*m - 1.f - 2.f*l);
        m = mu2[idx]; l = ls2[idx]; acc += (double)(expf(2.f*l) + m*m - 1.f - 2.f*l);
        m = mu3[idx]; l = ls3[idx]; acc += (double)(expf(2.f*l) + m*m - 1.f - 2.f*l);
    }
    __shared__ double sd[256];
    sd[tid] = acc;
    __syncthreads();
    for (int s = 128; s > 0; s >>= 1) {
        if (tid < s) sd[tid] += sd[tid + s];
        __syncthreads();
    }
    if (tid == 0) partials[blockIdx.x] = sd[0];
}

__global__ __launch_bounds__(256)
void kl_final_kernel(const double* __restrict__ partials, float* __restrict__ out_kl)
{
    const int tid = threadIdx.x;
    __shared__ double sd[256];
    sd[tid] = partials[tid];
    __syncthreads();
    for (int s = 128; s > 0; s >>= 1) {
        if (tid < s) sd[tid] += sd[tid + s];
        __syncthreads();
    }
    if (tid == 0) out_kl[0] = (float)(0.5 * sd[0]);
}

// ---------------------------------------------------------------------------
extern "C" void kernel_launch(void* const* d_in, const int* in_sizes, int n_in,
                              void* d_out, int out_size, void* d_ws, size_t ws_size,
                              hipStream_t stream)
{
    const float* x     = (const float*)d_in[0];
    const float* wq    = (const float*)d_in[1];
    const float* wq_ls = (const float*)d_in[2];
    const float* wk    = (const float*)d_in[3];
    const float* wk_ls = (const float*)d_in[4];
    const float* wv    = (const float*)d_in[5];
    const float* wv_ls = (const float*)d_in[6];
    const float* wo    = (const float*)d_in[7];
    const float* wo_ls = (const float*)d_in[8];
    const float* wo_b  = (const float*)d_in[9];
    const float* sq_w  = (const float*)d_in[10];
    const float* sq_b  = (const float*)d_in[11];
    const float* sk_w  = (const float*)d_in[12];
    const float* sk_b  = (const float*)d_in[13];
    float* out = (float*)d_out;

    float* ws = (float*)d_ws;
    float* qb = ws;                                   // 3145728 f
    float* kb = ws + 3145728;                         // 3145728 f
    // po (bf16, 4*3145728 shorts = 25 MB) overlays qb+kb, which are dead
    // after spd_kernel completes (stream-ordered).
    unsigned short* po  = (unsigned short*)ws;
    unsigned short* vt  = (unsigned short*)(ws + 6291456);   // 1572864 f
    unsigned short* xb  = (unsigned short*)(ws + 7864320);   // 1572864 f (re-used as attn bf16 out)
    unsigned short* wf  = (unsigned short*)(ws + 9437184);   // 884736 f
    unsigned short* wob = (unsigned short*)(ws + 10321920);  // 294912 f
    unsigned short* lqb = (unsigned short*)(ws + 10616832);  // 196608 f as bf16
    unsigned short* lkb = (unsigned short*)(ws + 10813440);  // 196608 f as bf16
    float* nqb = ws + 11010048;                       // 49152
    float* nkb = ws + 11059200;                       // 49152
    double* partials = (double*)(ws + 11108352);      // 256 doubles -> +512 f
    float* pwb = ws + 11108864;                       // 196608 f

    const dim3 b256(256);

    convert_kernel<<<dim3(1024, 5), b256, 0, stream>>>(x, wq, wk, wv, wo, xb, wf, wob);
    mfma_gemm<0><<<dim3(18, 32), b256, 0, stream>>>(xb, wf, nullptr, qb, kb, vt, nullptr);
    spd_kernel<<<dim3(1536, 2), b256, 0, stream>>>(qb, kb, sq_w, sq_b, sk_w, sk_b,
                                                   lqb, lkb, nqb, nkb);
    attn_kernel<<<dim3(16, BHD, 4), b256, 0, stream>>>(lqb, lkb, nqb, nkb, vt, po, pwb);
    attn_reduce<<<12288, b256, 0, stream>>>(po, pwb, xb);
    mfma_gemm<1><<<dim3(6, 32), b256, 0, stream>>>(xb, wob, wo_b, nullptr, nullptr, nullptr, out);
    kl_partial_kernel<<<256, b256, 0, stream>>>(wq, wq_ls, wk, wk_ls, wv, wv_ls,
                                                wo, wo_ls, partials);
    kl_final_kernel<<<1, b256, 0, stream>>>(partials, out + OUT_ELEMS);
}

// Round 6
// 245.138 us; speedup vs baseline: 1.1203x; 1.1203x over previous
//
#include <hip/hip_runtime.h>
#include <math.h>

#define HQ   12
#define DH   64
#define NSEQ 1024
#define BB   4
#define DIMM 768
#define RR   8
#define BHD  (BB*HQ)      // 48
#define MROWS (BB*NSEQ)   // 4096
#define OUT_ELEMS (BB*NSEQ*DIMM)  // 3145728

typedef short bf16x8 __attribute__((ext_vector_type(8)));
typedef float f32x4  __attribute__((ext_vector_type(4)));

__device__ __forceinline__ unsigned short f2bf(float f) {
    union { float f; unsigned u; } x; x.f = f;
    return (unsigned short)((x.u + 0x7fffu + ((x.u >> 16) & 1u)) >> 16);
}
__device__ __forceinline__ float bf2f(unsigned short b) {
    union { unsigned u; float f; } x; x.u = ((unsigned)b) << 16;
    return x.f;
}
// pack two fp32 -> bf16 pair (lo=w0, hi=w1) with +0x8000 rounding, 3 insts
__device__ __forceinline__ unsigned pack_bf16(float w0, float w1) {
    return __builtin_amdgcn_perm(__float_as_uint(w1) + 0x8000u,
                                 __float_as_uint(w0) + 0x8000u, 0x07060302u);
}

#define AS_GLOBAL(p) ((const __attribute__((address_space(1))) void*)(p))
#define AS_LDS(p)    ((__attribute__((address_space(3))) void*)(p))

// ---------------------------------------------------------------------------
// fp32 -> bf16 conversion: x (seg 0), wq/wk/wv -> fused wf (segs 1-3), wo (4)
// ---------------------------------------------------------------------------
__global__ __launch_bounds__(256)
void convert_kernel(const float* __restrict__ x,  const float* __restrict__ wq,
                    const float* __restrict__ wk, const float* __restrict__ wv,
                    const float* __restrict__ wo, unsigned short* __restrict__ xb,
                    unsigned short* __restrict__ wf, unsigned short* __restrict__ wob)
{
    const int seg = blockIdx.y;
    const float* src; unsigned short* dst; int n4;
    if      (seg == 0) { src = x;  dst = xb;            n4 = 786432; }
    else if (seg == 1) { src = wq; dst = wf;            n4 = 147456; }
    else if (seg == 2) { src = wk; dst = wf + 589824;   n4 = 147456; }
    else if (seg == 3) { src = wv; dst = wf + 1179648;  n4 = 147456; }
    else               { src = wo; dst = wob;           n4 = 147456; }
    for (int i = blockIdx.x*256 + threadIdx.x; i < n4; i += gridDim.x*256) {
        float4 v = ((const float4*)src)[i];
        unsigned lo = (unsigned)f2bf(v.x) | ((unsigned)f2bf(v.y) << 16);
        unsigned hi = (unsigned)f2bf(v.z) | ((unsigned)f2bf(v.w) << 16);
        ((uint2*)dst)[i] = make_uint2(lo, hi);
    }
}

// ---------------------------------------------------------------------------
// MFMA GEMM, m97 structure: 128x128 tile, BK=32, 4 waves x (4x4 16x16x32).
// MODE 0 (QKV fused, grid 18x32):
//   bx<6: Q -> qb fp32 (b,h,n,d); 6<=bx<12: K -> kb fp32 (b,h,n,d)
//   bx>=12: V with A/B swapped (acc = C^T) -> vt bf16 (bh,d,n)
// MODE 1 (O-proj, grid 6x32): A = attn bf16 [4096][768], out fp32 + bias
// ---------------------------------------------------------------------------
template<int MODE>
__global__ __launch_bounds__(256)
void mfma_gemm(const unsigned short* __restrict__ X,
               const unsigned short* __restrict__ Wf,
               const float* __restrict__ bias,
               float* __restrict__ qb, float* __restrict__ kb,
               unsigned short* __restrict__ vt, float* __restrict__ outp)
{
    __shared__ unsigned short As[128*32];   // 8 KB, unpadded (global_load_lds)
    __shared__ unsigned short Bs[128*32];
    const int tid  = threadIdx.x;
    const int lane = tid & 63;
    const int qr   = lane & 15, quad = lane >> 4;
    const int wid  = tid >> 6;
    const int w_m  = wid >> 1, w_n = wid & 1;
    const int bx = blockIdx.x, by = blockIdx.y;

    const bool vmode = (MODE == 0) && (bx >= 12);
    const unsigned short* Abase = vmode ? (Wf + bx*128*768) : (X + by*128*768);
    const unsigned short* Bbase = vmode ? (X + by*128*768) : (Wf + bx*128*768);

    const int row0 = tid >> 2;          // 0..63
    const int segk = (tid & 3) * 8;     // k offset 0/8/16/24

    f32x4 acc[4][4] = {};

    for (int kt = 0; kt < 768; kt += 32) {
        __syncthreads();   // previous tile fully consumed
        const unsigned short* ga = Abase + row0*768 + kt + segk;
        const unsigned short* gb = Bbase + row0*768 + kt + segk;
        __builtin_amdgcn_global_load_lds(AS_GLOBAL(ga),          AS_LDS(&As[tid*8]),        16, 0, 0);
        __builtin_amdgcn_global_load_lds(AS_GLOBAL(ga + 64*768), AS_LDS(&As[2048 + tid*8]), 16, 0, 0);
        __builtin_amdgcn_global_load_lds(AS_GLOBAL(gb),          AS_LDS(&Bs[tid*8]),        16, 0, 0);
        __builtin_amdgcn_global_load_lds(AS_GLOBAL(gb + 64*768), AS_LDS(&Bs[2048 + tid*8]), 16, 0, 0);
        __syncthreads();   // implicit vmcnt(0) drain

        bf16x8 a[4], b[4];
        #pragma unroll
        for (int mi = 0; mi < 4; ++mi)
            a[mi] = *(const bf16x8*)&As[(w_m*64 + mi*16 + qr)*32 + quad*8];
        #pragma unroll
        for (int ni = 0; ni < 4; ++ni)
            b[ni] = *(const bf16x8*)&Bs[(w_n*64 + ni*16 + qr)*32 + quad*8];
        #pragma unroll
        for (int mi = 0; mi < 4; ++mi)
            #pragma unroll
            for (int ni = 0; ni < 4; ++ni)
                acc[mi][ni] = __builtin_amdgcn_mfma_f32_16x16x32_bf16(a[mi], b[ni], acc[mi][ni], 0, 0, 0);
    }

    if (MODE == 1) {
        #pragma unroll
        for (int ni = 0; ni < 4; ++ni) {
            const int i = bx*128 + w_n*64 + ni*16 + qr;
            const float bs = bias[i];
            #pragma unroll
            for (int mi = 0; mi < 4; ++mi) {
                const int m0 = by*128 + w_m*64 + mi*16 + quad*4;
                #pragma unroll
                for (int r = 0; r < 4; ++r)
                    outp[(m0 + r)*768 + i] = acc[mi][ni][r] + bs;
            }
        }
    } else if (!vmode) {
        float* dst; int chb;
        if (bx < 6) { dst = qb; chb = bx*128; } else { dst = kb; chb = bx*128 - 768; }
        #pragma unroll
        for (int ni = 0; ni < 4; ++ni) {
            const int i = chb + w_n*64 + ni*16 + qr;
            const int h = i >> 6, d = i & 63;
            #pragma unroll
            for (int mi = 0; mi < 4; ++mi) {
                const int m0 = by*128 + w_m*64 + mi*16 + quad*4;
                #pragma unroll
                for (int r = 0; r < 4; ++r) {
                    const int m = m0 + r;
                    const int b = m >> 10, n = m & 1023;
                    dst[((((b*HQ + h) << 10) + n) << 6) + d] = acc[mi][ni][r];
                }
            }
        }
    } else {
        const int chb = bx*128 - 1536;
        #pragma unroll
        for (int mi = 0; mi < 4; ++mi) {
            #pragma unroll
            for (int r = 0; r < 4; ++r) {
                const int i = chb + w_m*64 + mi*16 + quad*4 + r;   // V channel
                const int h = i >> 6, d = i & 63;
                #pragma unroll
                for (int ni = 0; ni < 4; ++ni) {
                    const int mcol = by*128 + w_n*64 + ni*16 + qr; // seq index
                    const int b = mcol >> 10, n = mcol & 1023;
                    vt[((((b*HQ + h) << 6) + d) << 10) + n] = f2bf(acc[mi][ni][r]);
                }
            }
        }
    }
}

// ---------------------------------------------------------------------------
// SPD projection (q and k fused via blockIdx.y). Emits bf16 log-vectors +
// fp32 norms computed on the ROUNDED values (keeps d2 >= ~0 consistent).
// ---------------------------------------------------------------------------
__global__ __launch_bounds__(256)
void spd_kernel(const float* __restrict__ qb, const float* __restrict__ kb,
                const float* __restrict__ sqw, const float* __restrict__ sqb,
                const float* __restrict__ skw, const float* __restrict__ skb,
                unsigned short* __restrict__ lqo, unsigned short* __restrict__ lko,
                float* __restrict__ nqo, float* __restrict__ nko)
{
    const int which = blockIdx.y;
    const float* src = which ? kb  : qb;
    const float* wp0 = which ? skw : sqw;
    const float* bp  = which ? skb : sqb;
    unsigned short* lo = which ? lko : lqo;
    float* no = which ? nko : nqo;

    const int tid = threadIdx.x;
    const int r = tid & 7;
    const int row = blockIdx.x * 32 + (tid >> 3);
    const float* qp = src + row*64;
    const float* wp = wp0 + r*64;
    float acc = bp[r];
    #pragma unroll
    for (int d = 0; d < 64; ++d) acc += qp[d] * wp[d];
    float sp = (acc > 0.f) ? (acc + log1pf(__expf(-acc))) : log1pf(__expf(acc));
    float l = __logf(sp + 1e-6f + 1e-8f);
    const unsigned short lb = f2bf(l);
    lo[row*8 + r] = lb;
    const float lr = bf2f(lb);
    float s = lr * lr;
    s += __shfl_xor(s, 1);
    s += __shfl_xor(s, 2);
    s += __shfl_xor(s, 4);
    if (r == 0) no[row] = s;
}

// ---------------------------------------------------------------------------
// Attention v5: m97-style LDS staging. Grid (16,48): block = 64 queries of
// one bh, 4 waves. Per 64-key chunk, staged ONCE per block via
// global_load_lds(16B):
//   lk_s: 1 KB contiguous; vt_s: 8 KB, XOR-swizzled 16B groups
//   (group' = group ^ (row&7)) -> conflict-free ds_read_b128 B-frags from an
//   unpadded layout (global_load_lds requires lane-contiguous dest).
// S via MFMA (quad0 K-slots), weights = exp(-dist/8), packed bf16 via v_perm,
// PV via MFMA. Single pass (split-K reverted: R5 showed it's work-rate-bound).
// ---------------------------------------------------------------------------
__global__ __launch_bounds__(256)
void attn_kernel(const unsigned short* __restrict__ lq,
                 const unsigned short* __restrict__ lk,
                 const float* __restrict__ nq, const float* __restrict__ nk,
                 const unsigned short* __restrict__ vt,
                 unsigned short* __restrict__ out)
{
    __shared__ unsigned short lk_s[64*8];    // 1 KB
    __shared__ unsigned short vt_s[64*64];   // 8 KB, swizzled
    __shared__ unsigned short w_s[64*72];    // 9 KB, stride 72

    const int tid  = threadIdx.x;
    const int lane = tid & 63;
    const int wid  = tid >> 6;
    const int qr   = lane & 15;
    const int quad = lane >> 4;
    const int bh   = blockIdx.y;
    const int q0   = blockIdx.x*64 + wid*16;
    const int qrow = (bh << 10) + q0 + qr;
    const int bb   = bh / HQ;
    const int hh   = bh - bb*HQ;

    bf16x8 bq = {};
    if (quad == 0) bq = *(const bf16x8*)(lq + qrow*8);
    const float nqv = nq[qrow];

    f32x4 acc[4] = {};
    float wsum_acc = 0.f;

    const unsigned short* vtg = vt + (bh << 16);   // bh*64*1024
    const unsigned short* lkg = lk + (bh << 13);   // bh*1024*8
    const float*          nkg = nk + (bh << 10);

    // staging geometry: slot tid -> (row = tid>>3, group g = tid&7);
    // global col group = g ^ (row&7)  (row+32 has same row&7)
    const int srow = tid >> 3;
    const int scol = ((tid & 7) ^ (srow & 7)) << 3;

    for (int c = 0; c < NSEQ; c += 64) {
        __syncthreads();   // previous chunk fully consumed
        __builtin_amdgcn_global_load_lds(AS_GLOBAL(vtg + srow*1024 + c + scol),
                                         AS_LDS(&vt_s[tid*8]), 16, 0, 0);
        __builtin_amdgcn_global_load_lds(AS_GLOBAL(vtg + (srow + 32)*1024 + c + scol),
                                         AS_LDS(&vt_s[2048 + tid*8]), 16, 0, 0);
        if (tid < 64)
            __builtin_amdgcn_global_load_lds(AS_GLOBAL(lkg + (c + tid)*8),
                                             AS_LDS(&lk_s[tid*8]), 16, 0, 0);
        __syncthreads();   // vmcnt(0) drain

        // --- weights: lane covers q=qr, keys quad*4+r within each 16-key blk
        float wsum_c = 0.f;
        unsigned wpk[4][2];
        #pragma unroll
        for (int kb = 0; kb < 4; ++kb) {
            bf16x8 ak = {};
            if (quad == 0) ak = *(const bf16x8*)&lk_s[(kb*16 + qr)*8];
            f32x4 s = {};
            s = __builtin_amdgcn_mfma_f32_16x16x32_bf16(ak, bq, s, 0, 0, 0);
            const float4 nk4 = *(const float4*)(nkg + c + kb*16 + quad*4);
            const float nkv[4] = {nk4.x, nk4.y, nk4.z, nk4.w};
            float w[4];
            #pragma unroll
            for (int r = 0; r < 4; ++r) {
                const float d2 = nqv + nkv[r] - 2.f*s[r];
                const float dist = sqrtf(fmaxf(d2, 1e-12f));
                w[r] = __expf(-0.125f * dist);
                wsum_c += w[r];
            }
            wpk[kb][0] = pack_bf16(w[0], w[1]);
            wpk[kb][1] = pack_bf16(w[2], w[3]);
        }
        #pragma unroll
        for (int kb = 0; kb < 4; ++kb)
            *(uint2*)&w_s[(wid*16 + qr)*72 + kb*16 + quad*4] =
                make_uint2(wpk[kb][0], wpk[kb][1]);
        wsum_c += __shfl_xor(wsum_c, 16);
        wsum_c += __shfl_xor(wsum_c, 32);
        wsum_acc += wsum_c;

        // --- P·V via MFMA; B-frags from swizzled vt_s (conflict-free)
        #pragma unroll
        for (int s2 = 0; s2 < 2; ++s2) {
            const bf16x8 af = *(const bf16x8*)&w_s[(wid*16 + qr)*72 + s2*32 + quad*8];
            #pragma unroll
            for (int jb = 0; jb < 4; ++jb) {
                const int row = jb*16 + qr;
                const int grp = (s2*4 + quad) ^ (qr & 7);
                const bf16x8 bv = *(const bf16x8*)&vt_s[(row << 6) + (grp << 3)];
                acc[jb] = __builtin_amdgcn_mfma_f32_16x16x32_bf16(af, bv, acc[jb], 0, 0, 0);
            }
        }
    }

    // epilogue: normalize, store bf16 [b*1024+n][h*64+d] for the O-proj GEMM
    #pragma unroll
    for (int jb = 0; jb < 4; ++jb) {
        #pragma unroll
        for (int r = 0; r < 4; ++r) {
            const int row = quad*4 + r;
            const float wsd = __shfl(wsum_acc, row);
            const int qgl = q0 + row;
            const int d = jb*16 + qr;
            out[((bb << 10) + qgl)*768 + hh*64 + d] = f2bf(acc[jb][r] / wsd);
        }
    }
}

// ---------------------------------------------------------------------------
// KL reduction (unchanged)
// ---------------------------------------------------------------------------
__global__ __launch_bounds__(256)
void kl_partial_kernel(const float* __restrict__ mu0, const float* __restrict__ ls0,
                       const float* __restrict__ mu1, const float* __restrict__ ls1,
                       const float* __restrict__ mu2, const float* __restrict__ ls2,
                       const float* __restrict__ mu3, const float* __restrict__ ls3,
                       double* __restrict__ partials)
{
    const int tid = threadIdx.x;
    double acc = 0.0;
    for (int idx = blockIdx.x*256 + tid; idx < 589824; idx += 256*256) {
        float m, l;
        m = mu0[idx]; l = ls0[idx]; acc += (double)(expf(2.f*l) + m*m - 1.f - 2.f*l);
        m = mu1[idx]; l = ls1[idx]; acc += (double)(expf(2.f*l) + m*m - 1.f - 2.f*l);
        m = mu2[idx]; l = ls2[idx]; acc += (double)(expf(2.f*l) + m*m - 1.f - 2.f*l);
        m = mu3[idx]; l = ls3[idx]; acc += (double)(expf(2.f*l) + m*m - 1.f - 2.f*l);
    }
    __shared__ double sd[256];
    sd[tid] = acc;
    __syncthreads();
    for (int s = 128; s > 0; s >>= 1) {
        if (tid < s) sd[tid] += sd[tid + s];
        __syncthreads();
    }
    if (tid == 0) partials[blockIdx.x] = sd[0];
}

__global__ __launch_bounds__(256)
void kl_final_kernel(const double* __restrict__ partials, float* __restrict__ out_kl)
{
    const int tid = threadIdx.x;
    __shared__ double sd[256];
    sd[tid] = partials[tid];
    __syncthreads();
    for (int s = 128; s > 0; s >>= 1) {
        if (tid < s) sd[tid] += sd[tid + s];
        __syncthreads();
    }
    if (tid == 0) out_kl[0] = (float)(0.5 * sd[0]);
}

// ---------------------------------------------------------------------------
extern "C" void kernel_launch(void* const* d_in, const int* in_sizes, int n_in,
                              void* d_out, int out_size, void* d_ws, size_t ws_size,
                              hipStream_t stream)
{
    const float* x     = (const float*)d_in[0];
    const float* wq    = (const float*)d_in[1];
    const float* wq_ls = (const float*)d_in[2];
    const float* wk    = (const float*)d_in[3];
    const float* wk_ls = (const float*)d_in[4];
    const float* wv    = (const float*)d_in[5];
    const float* wv_ls = (const float*)d_in[6];
    const float* wo    = (const float*)d_in[7];
    const float* wo_ls = (const float*)d_in[8];
    const float* wo_b  = (const float*)d_in[9];
    const float* sq_w  = (const float*)d_in[10];
    const float* sq_b  = (const float*)d_in[11];
    const float* sk_w  = (const float*)d_in[12];
    const float* sk_b  = (const float*)d_in[13];
    float* out = (float*)d_out;

    float* ws = (float*)d_ws;
    float* qb = ws;                                   // 3145728 f
    float* kb = ws + 3145728;                         // 3145728 f
    unsigned short* vt  = (unsigned short*)(ws + 6291456);   // 1572864 f
    unsigned short* xb  = (unsigned short*)(ws + 7864320);   // 1572864 f (re-used as attn bf16 out)
    unsigned short* wf  = (unsigned short*)(ws + 9437184);   // 884736 f
    unsigned short* wob = (unsigned short*)(ws + 10321920);  // 294912 f
    unsigned short* lqb = (unsigned short*)(ws + 10616832);  // 196608 f as bf16
    unsigned short* lkb = (unsigned short*)(ws + 10813440);  // 196608 f as bf16
    float* nqb = ws + 11010048;                       // 49152
    float* nkb = ws + 11059200;                       // 49152
    double* partials = (double*)(ws + 11108352);      // 256 doubles

    const dim3 b256(256);

    convert_kernel<<<dim3(1024, 5), b256, 0, stream>>>(x, wq, wk, wv, wo, xb, wf, wob);
    mfma_gemm<0><<<dim3(18, 32), b256, 0, stream>>>(xb, wf, nullptr, qb, kb, vt, nullptr);
    spd_kernel<<<dim3(1536, 2), b256, 0, stream>>>(qb, kb, sq_w, sq_b, sk_w, sk_b,
                                                   lqb, lkb, nqb, nkb);
    attn_kernel<<<dim3(16, BHD), b256, 0, stream>>>(lqb, lkb, nqb, nkb, vt, xb);
    mfma_gemm<1><<<dim3(6, 32), b256, 0, stream>>>(xb, wob, wo_b, nullptr, nullptr, nullptr, out);
    kl_partial_kernel<<<256, b256, 0, stream>>>(wq, wq_ls, wk, wk_ls, wv, wv_ls,
                                                wo, wo_ls, partials);
    kl_final_kernel<<<1, b256, 0, stream>>>(partials, out + OUT_ELEMS);
}

// Round 7
// 235.564 us; speedup vs baseline: 1.1658x; 1.0406x over previous
//
#include <hip/hip_runtime.h>
#include <math.h>

#define HQ   12
#define DH   64
#define NSEQ 1024
#define BB   4
#define DIMM 768
#define RR   8
#define BHD  (BB*HQ)      // 48
#define MROWS (BB*NSEQ)   // 4096
#define OUT_ELEMS (BB*NSEQ*DIMM)  // 3145728

typedef short bf16x8 __attribute__((ext_vector_type(8)));
typedef float f32x4  __attribute__((ext_vector_type(4)));

__device__ __forceinline__ unsigned short f2bf(float f) {
    union { float f; unsigned u; } x; x.f = f;
    return (unsigned short)((x.u + 0x7fffu + ((x.u >> 16) & 1u)) >> 16);
}
__device__ __forceinline__ float bf2f(unsigned short b) {
    union { unsigned u; float f; } x; x.u = ((unsigned)b) << 16;
    return x.f;
}
// pack two fp32 -> bf16 pair (lo=w0, hi=w1) with +0x8000 rounding, 3 insts
__device__ __forceinline__ unsigned pack_bf16(float w0, float w1) {
    return __builtin_amdgcn_perm(__float_as_uint(w1) + 0x8000u,
                                 __float_as_uint(w0) + 0x8000u, 0x07060302u);
}

#define AS_GLOBAL(p) ((const __attribute__((address_space(1))) void*)(p))
#define AS_LDS(p)    ((__attribute__((address_space(3))) void*)(p))

// ---------------------------------------------------------------------------
// fp32 -> bf16: x (seg 0), wv (seg 1), wo (seg 2)
// ---------------------------------------------------------------------------
__global__ __launch_bounds__(256)
void convert_kernel(const float* __restrict__ x,  const float* __restrict__ wv,
                    const float* __restrict__ wo, unsigned short* __restrict__ xb,
                    unsigned short* __restrict__ wvb, unsigned short* __restrict__ wob)
{
    const int seg = blockIdx.y;
    const float* src; unsigned short* dst; int n4;
    if      (seg == 0) { src = x;  dst = xb;  n4 = 786432; }
    else if (seg == 1) { src = wv; dst = wvb; n4 = 147456; }
    else               { src = wo; dst = wob; n4 = 147456; }
    for (int i = blockIdx.x*256 + threadIdx.x; i < n4; i += gridDim.x*256) {
        float4 v = ((const float4*)src)[i];
        unsigned lo = (unsigned)f2bf(v.x) | ((unsigned)f2bf(v.y) << 16);
        unsigned hi = (unsigned)f2bf(v.z) | ((unsigned)f2bf(v.w) << 16);
        ((uint2*)dst)[i] = make_uint2(lo, hi);
    }
}

// ---------------------------------------------------------------------------
// Cqk[row, j] = sum_d sw[r,d] * W[h*64+d, j]   (row = g*96 + h*8 + r)
// Fuses the SPD projection into the QK weights: spd_pre = x . Cqk^T.
// grid (3, 192); j coalesced across threads; sw loads are wave-uniform.
// ---------------------------------------------------------------------------
__global__ __launch_bounds__(256)
void combine_kernel(const float* __restrict__ sqw, const float* __restrict__ wq,
                    const float* __restrict__ skw, const float* __restrict__ wk,
                    unsigned short* __restrict__ cqk)
{
    const int j   = blockIdx.x*256 + threadIdx.x;   // 0..767
    const int row = blockIdx.y;                     // 0..191
    const int g   = row >= 96;
    const int hr  = row - g*96;
    const int h   = hr >> 3, r = hr & 7;
    const float* sw = (g ? skw : sqw) + r*64;
    const float* W  = (g ? wk  : wq) + h*64*768 + j;
    float acc = 0.f;
    #pragma unroll
    for (int d = 0; d < 64; ++d) acc += sw[d] * W[d*768];
    cqk[row*768 + j] = f2bf(acc);
}

// ---------------------------------------------------------------------------
// lspd_gemm: spd_pre = x . Cqk^T  (M=4096, N=192, K=768), MFMA 128x64 tiles,
// grid (3,32), 4 waves x (32x64 = acc[2][4]). Epilogue fuses
// softplus -> log -> bf16, scatters to lq/lk (bh,n,r) layout.
// ---------------------------------------------------------------------------
__global__ __launch_bounds__(256)
void lspd_gemm(const unsigned short* __restrict__ X,
               const unsigned short* __restrict__ Cqk,
               const float* __restrict__ sqb, const float* __restrict__ skb,
               unsigned short* __restrict__ lqo, unsigned short* __restrict__ lko)
{
    __shared__ unsigned short As[128*32];   // 8 KB
    __shared__ unsigned short Bs[64*32];    // 4 KB
    const int tid  = threadIdx.x;
    const int lane = tid & 63;
    const int qr   = lane & 15, quad = lane >> 4;
    const int wid  = tid >> 6;
    const int bx = blockIdx.x, by = blockIdx.y;

    const int row0 = tid >> 2;
    const int segk = (tid & 3) * 8;

    f32x4 acc[2][4] = {};

    for (int kt = 0; kt < 768; kt += 32) {
        __syncthreads();
        const unsigned short* ga = X   + (by*128 + row0)*768 + kt + segk;
        const unsigned short* gb = Cqk + (bx*64  + row0)*768 + kt + segk;
        __builtin_amdgcn_global_load_lds(AS_GLOBAL(ga),          AS_LDS(&As[tid*8]),        16, 0, 0);
        __builtin_amdgcn_global_load_lds(AS_GLOBAL(ga + 64*768), AS_LDS(&As[2048 + tid*8]), 16, 0, 0);
        __builtin_amdgcn_global_load_lds(AS_GLOBAL(gb),          AS_LDS(&Bs[tid*8]),        16, 0, 0);
        __syncthreads();

        bf16x8 a[2], b[4];
        #pragma unroll
        for (int mi = 0; mi < 2; ++mi)
            a[mi] = *(const bf16x8*)&As[(wid*32 + mi*16 + qr)*32 + quad*8];
        #pragma unroll
        for (int ni = 0; ni < 4; ++ni)
            b[ni] = *(const bf16x8*)&Bs[(ni*16 + qr)*32 + quad*8];
        #pragma unroll
        for (int mi = 0; mi < 2; ++mi)
            #pragma unroll
            for (int ni = 0; ni < 4; ++ni)
                acc[mi][ni] = __builtin_amdgcn_mfma_f32_16x16x32_bf16(a[mi], b[ni], acc[mi][ni], 0, 0, 0);
    }

    // rr = (col & 7) == (qr & 7) for all cols this lane touches
    const float bq = sqb[qr & 7], bk = skb[qr & 7];
    #pragma unroll
    for (int ni = 0; ni < 4; ++ni) {
        const int c = bx*64 + ni*16 + qr;      // 0..191
        const int g = (c >= 96);               // wave-uniform per (bx,ni)
        const int cc = c - g*96;
        const int h = cc >> 3, rr = cc & 7;
        unsigned short* dst = g ? lko : lqo;
        const float bias = g ? bk : bq;
        #pragma unroll
        for (int mi = 0; mi < 2; ++mi) {
            #pragma unroll
            for (int r = 0; r < 4; ++r) {
                const int m = by*128 + wid*32 + mi*16 + quad*4 + r;
                const int b = m >> 10, n = m & 1023;
                const float pre = acc[mi][ni][r] + bias;
                const float sp = (pre > 0.f) ? (pre + log1pf(__expf(-pre)))
                                             : log1pf(__expf(pre));
                const float l = __logf(sp + 1e-6f + 1e-8f);
                dst[((((b*HQ + h) << 10) + n) << 3) + rr] = f2bf(l);
            }
        }
    }
}

// ---------------------------------------------------------------------------
// norms of the bf16 log-vectors: one thread per (g, bh, n). grid 384.
// ---------------------------------------------------------------------------
__global__ __launch_bounds__(256)
void norm_kernel(const unsigned short* __restrict__ lqo,
                 const unsigned short* __restrict__ lko,
                 float* __restrict__ nqo, float* __restrict__ nko)
{
    const int idx = blockIdx.x*256 + threadIdx.x;   // < 98304
    const int g = idx >= 49152;
    const int row = idx - g*49152;
    const unsigned short* src = (g ? lko : lqo) + row*8;
    float s = 0.f;
    #pragma unroll
    for (int r = 0; r < 8; ++r) { const float v = bf2f(src[r]); s += v*v; }
    (g ? nko : nqo)[row] = s;
}

// ---------------------------------------------------------------------------
// MFMA GEMM: MODE 0 = V-proj (A/B swapped, acc = C^T) -> vt bf16 (bh,d,n),
// grid (6,32). MODE 1 = O-proj, A = attn bf16 [4096][768], out fp32 + bias,
// grid (6,32). 128x128 tile, BK=32, 4 waves x (4x4 16x16x32).
// ---------------------------------------------------------------------------
template<int MODE>
__global__ __launch_bounds__(256)
void mfma_gemm(const unsigned short* __restrict__ X,
               const unsigned short* __restrict__ Wf,
               const float* __restrict__ bias,
               unsigned short* __restrict__ vt, float* __restrict__ outp)
{
    __shared__ unsigned short As[128*32];
    __shared__ unsigned short Bs[128*32];
    const int tid  = threadIdx.x;
    const int lane = tid & 63;
    const int qr   = lane & 15, quad = lane >> 4;
    const int wid  = tid >> 6;
    const int w_m  = wid >> 1, w_n = wid & 1;
    const int bx = blockIdx.x, by = blockIdx.y;

    const unsigned short* Abase = (MODE == 0) ? (Wf + bx*128*768) : (X + by*128*768);
    const unsigned short* Bbase = (MODE == 0) ? (X + by*128*768) : (Wf + bx*128*768);

    const int row0 = tid >> 2;
    const int segk = (tid & 3) * 8;

    f32x4 acc[4][4] = {};

    for (int kt = 0; kt < 768; kt += 32) {
        __syncthreads();
        const unsigned short* ga = Abase + row0*768 + kt + segk;
        const unsigned short* gb = Bbase + row0*768 + kt + segk;
        __builtin_amdgcn_global_load_lds(AS_GLOBAL(ga),          AS_LDS(&As[tid*8]),        16, 0, 0);
        __builtin_amdgcn_global_load_lds(AS_GLOBAL(ga + 64*768), AS_LDS(&As[2048 + tid*8]), 16, 0, 0);
        __builtin_amdgcn_global_load_lds(AS_GLOBAL(gb),          AS_LDS(&Bs[tid*8]),        16, 0, 0);
        __builtin_amdgcn_global_load_lds(AS_GLOBAL(gb + 64*768), AS_LDS(&Bs[2048 + tid*8]), 16, 0, 0);
        __syncthreads();

        bf16x8 a[4], b[4];
        #pragma unroll
        for (int mi = 0; mi < 4; ++mi)
            a[mi] = *(const bf16x8*)&As[(w_m*64 + mi*16 + qr)*32 + quad*8];
        #pragma unroll
        for (int ni = 0; ni < 4; ++ni)
            b[ni] = *(const bf16x8*)&Bs[(w_n*64 + ni*16 + qr)*32 + quad*8];
        #pragma unroll
        for (int mi = 0; mi < 4; ++mi)
            #pragma unroll
            for (int ni = 0; ni < 4; ++ni)
                acc[mi][ni] = __builtin_amdgcn_mfma_f32_16x16x32_bf16(a[mi], b[ni], acc[mi][ni], 0, 0, 0);
    }

    if (MODE == 1) {
        #pragma unroll
        for (int ni = 0; ni < 4; ++ni) {
            const int i = bx*128 + w_n*64 + ni*16 + qr;
            const float bs = bias[i];
            #pragma unroll
            for (int mi = 0; mi < 4; ++mi) {
                const int m0 = by*128 + w_m*64 + mi*16 + quad*4;
                #pragma unroll
                for (int r = 0; r < 4; ++r)
                    outp[(m0 + r)*768 + i] = acc[mi][ni][r] + bs;
            }
        }
    } else {
        const int chb = bx*128;
        #pragma unroll
        for (int mi = 0; mi < 4; ++mi) {
            #pragma unroll
            for (int r = 0; r < 4; ++r) {
                const int i = chb + w_m*64 + mi*16 + quad*4 + r;   // V channel
                const int h = i >> 6, d = i & 63;
                #pragma unroll
                for (int ni = 0; ni < 4; ++ni) {
                    const int mcol = by*128 + w_n*64 + ni*16 + qr; // seq index
                    const int b = mcol >> 10, n = mcol & 1023;
                    vt[((((b*HQ + h) << 6) + d) << 10) + n] = f2bf(acc[mi][ni][r]);
                }
            }
        }
    }
}

// ---------------------------------------------------------------------------
// Attention (unchanged from R6): m97-style LDS staging, S & P.V on MFMA.
// ---------------------------------------------------------------------------
__global__ __launch_bounds__(256)
void attn_kernel(const unsigned short* __restrict__ lq,
                 const unsigned short* __restrict__ lk,
                 const float* __restrict__ nq, const float* __restrict__ nk,
                 const unsigned short* __restrict__ vt,
                 unsigned short* __restrict__ out)
{
    __shared__ unsigned short lk_s[64*8];    // 1 KB
    __shared__ unsigned short vt_s[64*64];   // 8 KB, swizzled
    __shared__ unsigned short w_s[64*72];    // 9 KB, stride 72

    const int tid  = threadIdx.x;
    const int lane = tid & 63;
    const int wid  = tid >> 6;
    const int qr   = lane & 15;
    const int quad = lane >> 4;
    const int bh   = blockIdx.y;
    const int q0   = blockIdx.x*64 + wid*16;
    const int qrow = (bh << 10) + q0 + qr;
    const int bb   = bh / HQ;
    const int hh   = bh - bb*HQ;

    bf16x8 bq = {};
    if (quad == 0) bq = *(const bf16x8*)(lq + qrow*8);
    const float nqv = nq[qrow];

    f32x4 acc[4] = {};
    float wsum_acc = 0.f;

    const unsigned short* vtg = vt + (bh << 16);   // bh*64*1024
    const unsigned short* lkg = lk + (bh << 13);   // bh*1024*8
    const float*          nkg = nk + (bh << 10);

    const int srow = tid >> 3;
    const int scol = ((tid & 7) ^ (srow & 7)) << 3;

    for (int c = 0; c < NSEQ; c += 64) {
        __syncthreads();
        __builtin_amdgcn_global_load_lds(AS_GLOBAL(vtg + srow*1024 + c + scol),
                                         AS_LDS(&vt_s[tid*8]), 16, 0, 0);
        __builtin_amdgcn_global_load_lds(AS_GLOBAL(vtg + (srow + 32)*1024 + c + scol),
                                         AS_LDS(&vt_s[2048 + tid*8]), 16, 0, 0);
        if (tid < 64)
            __builtin_amdgcn_global_load_lds(AS_GLOBAL(lkg + (c + tid)*8),
                                             AS_LDS(&lk_s[tid*8]), 16, 0, 0);
        __syncthreads();

        float wsum_c = 0.f;
        unsigned wpk[4][2];
        #pragma unroll
        for (int kb = 0; kb < 4; ++kb) {
            bf16x8 ak = {};
            if (quad == 0) ak = *(const bf16x8*)&lk_s[(kb*16 + qr)*8];
            f32x4 s = {};
            s = __builtin_amdgcn_mfma_f32_16x16x32_bf16(ak, bq, s, 0, 0, 0);
            const float4 nk4 = *(const float4*)(nkg + c + kb*16 + quad*4);
            const float nkv[4] = {nk4.x, nk4.y, nk4.z, nk4.w};
            float w[4];
            #pragma unroll
            for (int r = 0; r < 4; ++r) {
                const float d2 = nqv + nkv[r] - 2.f*s[r];
                const float dist = sqrtf(fmaxf(d2, 1e-12f));
                w[r] = __expf(-0.125f * dist);
                wsum_c += w[r];
            }
            wpk[kb][0] = pack_bf16(w[0], w[1]);
            wpk[kb][1] = pack_bf16(w[2], w[3]);
        }
        #pragma unroll
        for (int kb = 0; kb < 4; ++kb)
            *(uint2*)&w_s[(wid*16 + qr)*72 + kb*16 + quad*4] =
                make_uint2(wpk[kb][0], wpk[kb][1]);
        wsum_c += __shfl_xor(wsum_c, 16);
        wsum_c += __shfl_xor(wsum_c, 32);
        wsum_acc += wsum_c;

        #pragma unroll
        for (int s2 = 0; s2 < 2; ++s2) {
            const bf16x8 af = *(const bf16x8*)&w_s[(wid*16 + qr)*72 + s2*32 + quad*8];
            #pragma unroll
            for (int jb = 0; jb < 4; ++jb) {
                const int row = jb*16 + qr;
                const int grp = (s2*4 + quad) ^ (qr & 7);
                const bf16x8 bv = *(const bf16x8*)&vt_s[(row << 6) + (grp << 3)];
                acc[jb] = __builtin_amdgcn_mfma_f32_16x16x32_bf16(af, bv, acc[jb], 0, 0, 0);
            }
        }
    }

    #pragma unroll
    for (int jb = 0; jb < 4; ++jb) {
        #pragma unroll
        for (int r = 0; r < 4; ++r) {
            const int row = quad*4 + r;
            const float wsd = __shfl(wsum_acc, row);
            const int qgl = q0 + row;
            const int d = jb*16 + qr;
            out[((bb << 10) + qgl)*768 + hh*64 + d] = f2bf(acc[jb][r] / wsd);
        }
    }
}

// ---------------------------------------------------------------------------
// KL reduction (unchanged)
// ---------------------------------------------------------------------------
__global__ __launch_bounds__(256)
void kl_partial_kernel(const float* __restrict__ mu0, const float* __restrict__ ls0,
                       const float* __restrict__ mu1, const float* __restrict__ ls1,
                       const float* __restrict__ mu2, const float* __restrict__ ls2,
                       const float* __restrict__ mu3, const float* __restrict__ ls3,
                       double* __restrict__ partials)
{
    const int tid = threadIdx.x;
    double acc = 0.0;
    for (int idx = blockIdx.x*256 + tid; idx < 589824; idx += 256*256) {
        float m, l;
        m = mu0[idx]; l = ls0[idx]; acc += (double)(expf(2.f*l) + m*m - 1.f - 2.f*l);
        m = mu1[idx]; l = ls1[idx]; acc += (double)(expf(2.f*l) + m*m - 1.f - 2.f*l);
        m = mu2[idx]; l = ls2[idx]; acc += (double)(expf(2.f*l) + m*m - 1.f - 2.f*l);
        m = mu3[idx]; l = ls3[idx]; acc += (double)(expf(2.f*l) + m*m - 1.f - 2.f*l);
    }
    __shared__ double sd[256];
    sd[tid] = acc;
    __syncthreads();
    for (int s = 128; s > 0; s >>= 1) {
        if (tid < s) sd[tid] += sd[tid + s];
        __syncthreads();
    }
    if (tid == 0) partials[blockIdx.x] = sd[0];
}

__global__ __launch_bounds__(256)
void kl_final_kernel(const double* __restrict__ partials, float* __restrict__ out_kl)
{
    const int tid = threadIdx.x;
    __shared__ double sd[256];
    sd[tid] = partials[tid];
    __syncthreads();
    for (int s = 128; s > 0; s >>= 1) {
        if (tid < s) sd[tid] += sd[tid + s];
        __syncthreads();
    }
    if (tid == 0) out_kl[0] = (float)(0.5 * sd[0]);
}

// ---------------------------------------------------------------------------
extern "C" void kernel_launch(void* const* d_in, const int* in_sizes, int n_in,
                              void* d_out, int out_size, void* d_ws, size_t ws_size,
                              hipStream_t stream)
{
    const float* x     = (const float*)d_in[0];
    const float* wq    = (const float*)d_in[1];
    const float* wq_ls = (const float*)d_in[2];
    const float* wk    = (const float*)d_in[3];
    const float* wk_ls = (const float*)d_in[4];
    const float* wv    = (const float*)d_in[5];
    const float* wv_ls = (const float*)d_in[6];
    const float* wo    = (const float*)d_in[7];
    const float* wo_ls = (const float*)d_in[8];
    const float* wo_b  = (const float*)d_in[9];
    const float* sq_w  = (const float*)d_in[10];
    const float* sq_b  = (const float*)d_in[11];
    const float* sk_w  = (const float*)d_in[12];
    const float* sk_b  = (const float*)d_in[13];
    float* out = (float*)d_out;

    float* ws = (float*)d_ws;
    unsigned short* vt  = (unsigned short*)ws;                 // 1572864 f
    unsigned short* xb  = (unsigned short*)(ws + 1572864);     // 1572864 f (re-used as attn out)
    unsigned short* wvb = (unsigned short*)(ws + 3145728);     // 294912 f
    unsigned short* wob = (unsigned short*)(ws + 3440640);     // 294912 f
    unsigned short* cqk = (unsigned short*)(ws + 3735552);     // 73728 f
    unsigned short* lqb = (unsigned short*)(ws + 3809280);     // 196608 f
    unsigned short* lkb = (unsigned short*)(ws + 4005888);     // 196608 f
    float* nqb = ws + 4202496;                                 // 49152 f
    float* nkb = ws + 4251648;                                 // 49152 f
    double* partials = (double*)(ws + 4300800);                // 256 doubles

    const dim3 b256(256);

    convert_kernel<<<dim3(1024, 3), b256, 0, stream>>>(x, wv, wo, xb, wvb, wob);
    combine_kernel<<<dim3(3, 192), b256, 0, stream>>>(sq_w, wq, sk_w, wk, cqk);
    lspd_gemm<<<dim3(3, 32), b256, 0, stream>>>(xb, cqk, sq_b, sk_b, lqb, lkb);
    mfma_gemm<0><<<dim3(6, 32), b256, 0, stream>>>(xb, wvb, nullptr, vt, nullptr);
    norm_kernel<<<384, b256, 0, stream>>>(lqb, lkb, nqb, nkb);
    attn_kernel<<<dim3(16, BHD), b256, 0, stream>>>(lqb, lkb, nqb, nkb, vt, xb);
    mfma_gemm<1><<<dim3(6, 32), b256, 0, stream>>>(xb, wob, wo_b, nullptr, out);
    kl_partial_kernel<<<256, b256, 0, stream>>>(wq, wq_ls, wk, wk_ls, wv, wv_ls,
                                                wo, wo_ls, partials);
    kl_final_kernel<<<1, b256, 0, stream>>>(partials, out + OUT_ELEMS);
}

// Round 8
// 198.151 us; speedup vs baseline: 1.3859x; 1.1888x over previous
//
#include <hip/hip_runtime.h>
#include <math.h>

#define HQ   12
#define DH   64
#define NSEQ 1024
#define BB   4
#define DIMM 768
#define RR   8
#define BHD  (BB*HQ)      // 48
#define MROWS (BB*NSEQ)   // 4096
#define OUT_ELEMS (BB*NSEQ*DIMM)  // 3145728

typedef short bf16x8 __attribute__((ext_vector_type(8)));
typedef float f32x4  __attribute__((ext_vector_type(4)));

__device__ __forceinline__ unsigned short f2bf(float f) {
    union { float f; unsigned u; } x; x.f = f;
    return (unsigned short)((x.u + 0x7fffu + ((x.u >> 16) & 1u)) >> 16);
}
__device__ __forceinline__ float bf2f(unsigned short b) {
    union { unsigned u; float f; } x; x.u = ((unsigned)b) << 16;
    return x.f;
}
// pack two fp32 -> bf16 pair (lo=w0, hi=w1) with +0x8000 rounding, 3 insts
__device__ __forceinline__ unsigned pack_bf16(float w0, float w1) {
    return __builtin_amdgcn_perm(__float_as_uint(w1) + 0x8000u,
                                 __float_as_uint(w0) + 0x8000u, 0x07060302u);
}

#define AS_GLOBAL(p) ((const __attribute__((address_space(1))) void*)(p))
#define AS_LDS(p)    ((__attribute__((address_space(3))) void*)(p))

// ---------------------------------------------------------------------------
// prep: seg 0-2 convert x/wv/wo to bf16; seg 3-6 KL partials (64 blocks each,
// block-level double reduce + one atomicAdd); seg 7 combine Cqk.
// ---------------------------------------------------------------------------
__global__ __launch_bounds__(256)
void prep_kernel(const float* __restrict__ x,  const float* __restrict__ wv,
                 const float* __restrict__ wo, const float* __restrict__ wq,
                 const float* __restrict__ wq_ls, const float* __restrict__ wk,
                 const float* __restrict__ wk_ls, const float* __restrict__ wv_ls,
                 const float* __restrict__ wo_ls, const float* __restrict__ sqw,
                 const float* __restrict__ skw,
                 unsigned short* __restrict__ xb, unsigned short* __restrict__ wvb,
                 unsigned short* __restrict__ wob, unsigned short* __restrict__ cqk,
                 double* __restrict__ klacc)
{
    __shared__ double sd[256];
    const int seg = blockIdx.y;
    const int tid = threadIdx.x;
    const int bx  = blockIdx.x;

    if (seg <= 2) {
        const float* src = (seg == 0) ? x : (seg == 1) ? wv : wo;
        unsigned short* dst = (seg == 0) ? xb : (seg == 1) ? wvb : wob;
        const int n4 = (seg == 0) ? 786432 : 147456;
        for (int i = bx*256 + tid; i < n4; i += 1024*256) {
            float4 v = ((const float4*)src)[i];
            ((uint2*)dst)[i] = make_uint2(pack_bf16(v.x, v.y), pack_bf16(v.z, v.w));
        }
    } else if (seg <= 6) {
        if (bx >= 64) return;
        const float *mu, *ls;
        if      (seg == 3) { mu = wq; ls = wq_ls; }
        else if (seg == 4) { mu = wk; ls = wk_ls; }
        else if (seg == 5) { mu = wv; ls = wv_ls; }
        else               { mu = wo; ls = wo_ls; }
        double acc = 0.0;
        for (int i = bx*256 + tid; i < 147456; i += 64*256) {
            float4 m4 = ((const float4*)mu)[i];
            float4 l4 = ((const float4*)ls)[i];
            acc += (double)(expf(2.f*l4.x) + m4.x*m4.x - 1.f - 2.f*l4.x);
            acc += (double)(expf(2.f*l4.y) + m4.y*m4.y - 1.f - 2.f*l4.y);
            acc += (double)(expf(2.f*l4.z) + m4.z*m4.z - 1.f - 2.f*l4.z);
            acc += (double)(expf(2.f*l4.w) + m4.w*m4.w - 1.f - 2.f*l4.w);
        }
        sd[tid] = acc;
        __syncthreads();
        for (int s = 128; s > 0; s >>= 1) {
            if (tid < s) sd[tid] += sd[tid + s];
            __syncthreads();
        }
        if (tid == 0) atomicAdd(klacc, sd[0]);
    } else {
        if (bx >= 576) return;
        const int j   = (bx % 3)*256 + tid;
        const int row = bx / 3;                  // 0..191
        const int g   = row >= 96;
        const int hr  = row - g*96;
        const int h   = hr >> 3, r = hr & 7;
        const float* sw = (g ? skw : sqw) + r*64;
        const float* W  = (g ? wk  : wq) + h*64*768 + j;
        float acc = 0.f;
        #pragma unroll
        for (int d = 0; d < 64; ++d) acc += sw[d] * W[d*768];
        cqk[row*768 + j] = f2bf(acc);
    }
}

// ---------------------------------------------------------------------------
// lspd_gemm: spd_pre = x . Cqk^T (M=4096, N=192, K=768). 64x64 tiles,
// grid (3,64) = 192 blocks; 4 waves 2x2, wave = 32x32 (acc[2][2]).
// Epilogue fuses softplus->log->bf16 scatter AND the norm reduction
// (shfl_xor over the 8 r-lanes of each (h,n)).
// ---------------------------------------------------------------------------
__global__ __launch_bounds__(256)
void lspd_gemm(const unsigned short* __restrict__ X,
               const unsigned short* __restrict__ Cqk,
               const float* __restrict__ sqb, const float* __restrict__ skb,
               unsigned short* __restrict__ lqo, unsigned short* __restrict__ lko,
               float* __restrict__ nqo, float* __restrict__ nko)
{
    __shared__ unsigned short As[64*32];    // 4 KB
    __shared__ unsigned short Bs[64*32];    // 4 KB
    const int tid  = threadIdx.x;
    const int lane = tid & 63;
    const int qr   = lane & 15, quad = lane >> 4;
    const int wid  = tid >> 6;
    const int w_m  = wid >> 1, w_n = wid & 1;
    const int bx = blockIdx.x, by = blockIdx.y;
    const int row0 = tid >> 2;
    const int segk = (tid & 3) * 8;

    f32x4 acc[2][2] = {};

    for (int kt = 0; kt < 768; kt += 32) {
        __syncthreads();
        __builtin_amdgcn_global_load_lds(AS_GLOBAL(X   + (by*64 + row0)*768 + kt + segk),
                                         AS_LDS(&As[tid*8]), 16, 0, 0);
        __builtin_amdgcn_global_load_lds(AS_GLOBAL(Cqk + (bx*64 + row0)*768 + kt + segk),
                                         AS_LDS(&Bs[tid*8]), 16, 0, 0);
        __syncthreads();

        bf16x8 a[2], b[2];
        #pragma unroll
        for (int mi = 0; mi < 2; ++mi)
            a[mi] = *(const bf16x8*)&As[(w_m*32 + mi*16 + qr)*32 + quad*8];
        #pragma unroll
        for (int ni = 0; ni < 2; ++ni)
            b[ni] = *(const bf16x8*)&Bs[(w_n*32 + ni*16 + qr)*32 + quad*8];
        #pragma unroll
        for (int mi = 0; mi < 2; ++mi)
            #pragma unroll
            for (int ni = 0; ni < 2; ++ni)
                acc[mi][ni] = __builtin_amdgcn_mfma_f32_16x16x32_bf16(a[mi], b[ni], acc[mi][ni], 0, 0, 0);
    }

    const int rr = qr & 7;
    #pragma unroll
    for (int ni = 0; ni < 2; ++ni) {
        const int c = bx*64 + w_n*32 + ni*16 + qr;   // 0..191
        const int g = (c >= 96);                     // uniform over qr-16 span
        const int cc = c - g*96;
        const int h = cc >> 3;
        unsigned short* dst = g ? lko : lqo;
        float* ndst = g ? nko : nqo;
        const float bias = (g ? skb : sqb)[rr];
        #pragma unroll
        for (int mi = 0; mi < 2; ++mi) {
            #pragma unroll
            for (int r = 0; r < 4; ++r) {
                const int m = by*64 + w_m*32 + mi*16 + quad*4 + r;
                const int b = m >> 10, n = m & 1023;
                const float pre = acc[mi][ni][r] + bias;
                const float sp = (pre > 0.f) ? (pre + log1pf(__expf(-pre)))
                                             : log1pf(__expf(pre));
                const float l = __logf(sp + 1e-6f + 1e-8f);
                const unsigned short lb = f2bf(l);
                const int base = ((b*HQ + h) << 10) + n;
                dst[(base << 3) + rr] = lb;
                const float lr = bf2f(lb);
                float sq = lr * lr;
                sq += __shfl_xor(sq, 1);
                sq += __shfl_xor(sq, 2);
                sq += __shfl_xor(sq, 4);
                if (rr == 0) ndst[base] = sq;
            }
        }
    }
}

// ---------------------------------------------------------------------------
// MFMA GEMM, 64x64 tiles, grid (12,64) = 768 blocks (3 blocks/CU).
// MODE 0 = V-proj (A/B swapped, acc = C^T) -> vt bf16 (bh,d,n)
// MODE 1 = O-proj, out fp32 + bias; block (0,0) also writes the KL scalar.
// ---------------------------------------------------------------------------
template<int MODE>
__global__ __launch_bounds__(256)
void mfma_gemm(const unsigned short* __restrict__ X,
               const unsigned short* __restrict__ Wf,
               const float* __restrict__ bias,
               unsigned short* __restrict__ vt, float* __restrict__ outp,
               const double* __restrict__ klacc)
{
    __shared__ unsigned short As[64*32];
    __shared__ unsigned short Bs[64*32];
    const int tid  = threadIdx.x;
    const int lane = tid & 63;
    const int qr   = lane & 15, quad = lane >> 4;
    const int wid  = tid >> 6;
    const int w_m  = wid >> 1, w_n = wid & 1;
    const int bx = blockIdx.x, by = blockIdx.y;

    const unsigned short* Abase = (MODE == 0) ? (Wf + bx*64*768) : (X + by*64*768);
    const unsigned short* Bbase = (MODE == 0) ? (X + by*64*768) : (Wf + bx*64*768);

    const int row0 = tid >> 2;
    const int segk = (tid & 3) * 8;

    f32x4 acc[2][2] = {};

    for (int kt = 0; kt < 768; kt += 32) {
        __syncthreads();
        __builtin_amdgcn_global_load_lds(AS_GLOBAL(Abase + row0*768 + kt + segk),
                                         AS_LDS(&As[tid*8]), 16, 0, 0);
        __builtin_amdgcn_global_load_lds(AS_GLOBAL(Bbase + row0*768 + kt + segk),
                                         AS_LDS(&Bs[tid*8]), 16, 0, 0);
        __syncthreads();

        bf16x8 a[2], b[2];
        #pragma unroll
        for (int mi = 0; mi < 2; ++mi)
            a[mi] = *(const bf16x8*)&As[(w_m*32 + mi*16 + qr)*32 + quad*8];
        #pragma unroll
        for (int ni = 0; ni < 2; ++ni)
            b[ni] = *(const bf16x8*)&Bs[(w_n*32 + ni*16 + qr)*32 + quad*8];
        #pragma unroll
        for (int mi = 0; mi < 2; ++mi)
            #pragma unroll
            for (int ni = 0; ni < 2; ++ni)
                acc[mi][ni] = __builtin_amdgcn_mfma_f32_16x16x32_bf16(a[mi], b[ni], acc[mi][ni], 0, 0, 0);
    }

    if (MODE == 1) {
        #pragma unroll
        for (int ni = 0; ni < 2; ++ni) {
            const int i = bx*64 + w_n*32 + ni*16 + qr;
            const float bs = bias[i];
            #pragma unroll
            for (int mi = 0; mi < 2; ++mi) {
                const int m0 = by*64 + w_m*32 + mi*16 + quad*4;
                #pragma unroll
                for (int r = 0; r < 4; ++r)
                    outp[(m0 + r)*768 + i] = acc[mi][ni][r] + bs;
            }
        }
        if (bx == 0 && by == 0 && tid == 0)
            outp[OUT_ELEMS] = (float)(0.5 * klacc[0]);
    } else {
        const int bidx = (by*64) >> 10;              // batch (uniform per by)
        #pragma unroll
        for (int mi = 0; mi < 2; ++mi) {
            #pragma unroll
            for (int r = 0; r < 4; ++r) {
                const int i = bx*64 + w_m*32 + mi*16 + quad*4 + r;  // V channel
                const int h = i >> 6, d = i & 63;
                #pragma unroll
                for (int ni = 0; ni < 2; ++ni) {
                    const int n = by*64 + w_n*32 + ni*16 + qr;      // seq (global)
                    vt[((((bidx*HQ + h) << 6) + d) << 10) + (n & 1023)] = f2bf(acc[mi][ni][r]);
                }
            }
        }
    }
}

// ---------------------------------------------------------------------------
// Attention: m97-style LDS staging, S & P.V on MFMA (R6 structure).
// sqrt via raw v_sqrt_f32; exp via native exp2 with folded scale.
// ---------------------------------------------------------------------------
__global__ __launch_bounds__(256)
void attn_kernel(const unsigned short* __restrict__ lq,
                 const unsigned short* __restrict__ lk,
                 const float* __restrict__ nq, const float* __restrict__ nk,
                 const unsigned short* __restrict__ vt,
                 unsigned short* __restrict__ out)
{
    __shared__ unsigned short lk_s[64*8];    // 1 KB
    __shared__ unsigned short vt_s[64*64];   // 8 KB, swizzled
    __shared__ unsigned short w_s[64*72];    // 9 KB, stride 72

    const int tid  = threadIdx.x;
    const int lane = tid & 63;
    const int wid  = tid >> 6;
    const int qr   = lane & 15;
    const int quad = lane >> 4;
    const int bh   = blockIdx.y;
    const int q0   = blockIdx.x*64 + wid*16;
    const int qrow = (bh << 10) + q0 + qr;
    const int bb   = bh / HQ;
    const int hh   = bh - bb*HQ;

    bf16x8 bq = {};
    if (quad == 0) bq = *(const bf16x8*)(lq + qrow*8);
    const float nqv = nq[qrow];

    f32x4 acc[4] = {};
    float wsum_acc = 0.f;

    const unsigned short* vtg = vt + (bh << 16);   // bh*64*1024
    const unsigned short* lkg = lk + (bh << 13);   // bh*1024*8
    const float*          nkg = nk + (bh << 10);

    const int srow = tid >> 3;
    const int scol = ((tid & 7) ^ (srow & 7)) << 3;
    const float EXP2S = -0.1803368801f;            // -0.125 * log2(e)

    for (int c = 0; c < NSEQ; c += 64) {
        __syncthreads();
        __builtin_amdgcn_global_load_lds(AS_GLOBAL(vtg + srow*1024 + c + scol),
                                         AS_LDS(&vt_s[tid*8]), 16, 0, 0);
        __builtin_amdgcn_global_load_lds(AS_GLOBAL(vtg + (srow + 32)*1024 + c + scol),
                                         AS_LDS(&vt_s[2048 + tid*8]), 16, 0, 0);
        if (tid < 64)
            __builtin_amdgcn_global_load_lds(AS_GLOBAL(lkg + (c + tid)*8),
                                             AS_LDS(&lk_s[tid*8]), 16, 0, 0);
        __syncthreads();

        float wsum_c = 0.f;
        unsigned wpk[4][2];
        #pragma unroll
        for (int kb = 0; kb < 4; ++kb) {
            bf16x8 ak = {};
            if (quad == 0) ak = *(const bf16x8*)&lk_s[(kb*16 + qr)*8];
            f32x4 s = {};
            s = __builtin_amdgcn_mfma_f32_16x16x32_bf16(ak, bq, s, 0, 0, 0);
            const float4 nk4 = *(const float4*)(nkg + c + kb*16 + quad*4);
            const float nkv[4] = {nk4.x, nk4.y, nk4.z, nk4.w};
            float w[4];
            #pragma unroll
            for (int r = 0; r < 4; ++r) {
                const float d2 = fmaf(-2.f, s[r], nqv + nkv[r]);
                const float dist = __builtin_amdgcn_sqrtf(fmaxf(d2, 1e-12f));
                w[r] = exp2f(dist * EXP2S);
                wsum_c += w[r];
            }
            wpk[kb][0] = pack_bf16(w[0], w[1]);
            wpk[kb][1] = pack_bf16(w[2], w[3]);
        }
        #pragma unroll
        for (int kb = 0; kb < 4; ++kb)
            *(uint2*)&w_s[(wid*16 + qr)*72 + kb*16 + quad*4] =
                make_uint2(wpk[kb][0], wpk[kb][1]);
        wsum_c += __shfl_xor(wsum_c, 16);
        wsum_c += __shfl_xor(wsum_c, 32);
        wsum_acc += wsum_c;

        #pragma unroll
        for (int s2 = 0; s2 < 2; ++s2) {
            const bf16x8 af = *(const bf16x8*)&w_s[(wid*16 + qr)*72 + s2*32 + quad*8];
            #pragma unroll
            for (int jb = 0; jb < 4; ++jb) {
                const int row = jb*16 + qr;
                const int grp = (s2*4 + quad) ^ (qr & 7);
                const bf16x8 bv = *(const bf16x8*)&vt_s[(row << 6) + (grp << 3)];
                acc[jb] = __builtin_amdgcn_mfma_f32_16x16x32_bf16(af, bv, acc[jb], 0, 0, 0);
            }
        }
    }

    #pragma unroll
    for (int jb = 0; jb < 4; ++jb) {
        #pragma unroll
        for (int r = 0; r < 4; ++r) {
            const int row = quad*4 + r;
            const float wsd = __shfl(wsum_acc, row);
            const int qgl = q0 + row;
            const int d = jb*16 + qr;
            out[((bb << 10) + qgl)*768 + hh*64 + d] = f2bf(acc[jb][r] / wsd);
        }
    }
}

// ---------------------------------------------------------------------------
extern "C" void kernel_launch(void* const* d_in, const int* in_sizes, int n_in,
                              void* d_out, int out_size, void* d_ws, size_t ws_size,
                              hipStream_t stream)
{
    const float* x     = (const float*)d_in[0];
    const float* wq    = (const float*)d_in[1];
    const float* wq_ls = (const float*)d_in[2];
    const float* wk    = (const float*)d_in[3];
    const float* wk_ls = (const float*)d_in[4];
    const float* wv    = (const float*)d_in[5];
    const float* wv_ls = (const float*)d_in[6];
    const float* wo    = (const float*)d_in[7];
    const float* wo_ls = (const float*)d_in[8];
    const float* wo_b  = (const float*)d_in[9];
    const float* sq_w  = (const float*)d_in[10];
    const float* sq_b  = (const float*)d_in[11];
    const float* sk_w  = (const float*)d_in[12];
    const float* sk_b  = (const float*)d_in[13];
    float* out = (float*)d_out;

    float* ws = (float*)d_ws;
    unsigned short* vt  = (unsigned short*)ws;                 // 1572864 f
    unsigned short* xb  = (unsigned short*)(ws + 1572864);     // 1572864 f (re-used as attn out)
    unsigned short* wvb = (unsigned short*)(ws + 3145728);     // 294912 f
    unsigned short* wob = (unsigned short*)(ws + 3440640);     // 294912 f
    unsigned short* cqk = (unsigned short*)(ws + 3735552);     // 73728 f
    unsigned short* lqb = (unsigned short*)(ws + 3809280);     // 196608 f
    unsigned short* lkb = (unsigned short*)(ws + 4005888);     // 196608 f
    float* nqb = ws + 4202496;                                 // 49152 f
    float* nkb = ws + 4251648;                                 // 49152 f
    double* klacc = (double*)(ws + 4300800);                   // 1 double

    const dim3 b256(256);

    hipMemsetAsync(klacc, 0, sizeof(double), stream);
    prep_kernel<<<dim3(1024, 8), b256, 0, stream>>>(
        x, wv, wo, wq, wq_ls, wk, wk_ls, wv_ls, wo_ls, sq_w, sk_w,
        xb, wvb, wob, cqk, klacc);
    lspd_gemm<<<dim3(3, 64), b256, 0, stream>>>(xb, cqk, sq_b, sk_b,
                                                lqb, lkb, nqb, nkb);
    mfma_gemm<0><<<dim3(12, 64), b256, 0, stream>>>(xb, wvb, nullptr, vt, nullptr, nullptr);
    attn_kernel<<<dim3(16, BHD), b256, 0, stream>>>(lqb, lkb, nqb, nkb, vt, xb);
    mfma_gemm<1><<<dim3(12, 64), b256, 0, stream>>>(xb, wob, wo_b, nullptr, out, klacc);
}